// Round 6
// baseline (355.320 us; speedup 1.0000x reference)
//
#include <hip/hip_runtime.h>
#include <hip/hip_bf16.h>

// GCN forward, CSR-gather + split-bf16 MFMA:
//   dinv[v] = rsqrt(1 + indeg[v])
//   y  = dinv .* (x @ W1)        fp32 out; GEMM via 3-term split-bf16 MFMA
//   h[v] = relu(dinv[v]*(y[v] + sum_in y[u]) + b1)    (gather phase, fp32)
//   z  = dinv .* (h @ W2)        fp32 out; split-bf16 MFMA, swizzled LDS h-tiles
//   out[g] = mean_v dinv[v]*(z[v] + sum_in z[u]) + b2

typedef __attribute__((ext_vector_type(8))) short short8;
typedef __attribute__((ext_vector_type(4))) float f32x4;

__device__ __forceinline__ void atomAddF(float* p, float v) { unsafeAtomicAdd(p, v); }

__device__ __forceinline__ unsigned short bf_rne(float f) {
  unsigned int u = __float_as_uint(f);
  return (unsigned short)((u + 0x7fffu + ((u >> 16) & 1u)) >> 16);
}
__device__ __forceinline__ float bf2f(unsigned short h) {
  return __uint_as_float(((unsigned int)h) << 16);
}

// ---------- prep: W -> transposed split-bf16 ----------
__global__ __launch_bounds__(256) void k_prepw(const float* __restrict__ W1,
    const float* __restrict__ W2,
    unsigned short* __restrict__ W1th, unsigned short* __restrict__ W1tl,
    unsigned short* __restrict__ W2th, unsigned short* __restrict__ W2tl) {
  int i = blockIdx.x * 256 + threadIdx.x;
  if (i < 16384) {
    int c = i >> 7, k = i & 127;
    float f = W1[k * 128 + c];
    unsigned short hi = bf_rne(f);
    W1th[i] = hi;
    W1tl[i] = bf_rne(f - bf2f(hi));
  } else if (i < 16384 + 8192) {
    int j = i - 16384;
    int c = j >> 7, k = j & 127;
    float f = W2[k * 64 + c];
    unsigned short hi = bf_rne(f);
    W2th[j] = hi;
    W2tl[j] = bf_rne(f - bf2f(hi));
  }
}

// ---------- degree / CSR build ----------
__global__ __launch_bounds__(256) void k_count(const int* __restrict__ col,
                                               int* __restrict__ deg, int E) {
  int e = blockIdx.x * 256 + threadIdx.x;
  if (e < E) atomicAdd(&deg[col[e]], 1);
}

__global__ __launch_bounds__(256) void k_blocksum(const int* __restrict__ deg,
                                                  int* __restrict__ partial, int N) {
  __shared__ int sh[256];
  int t = threadIdx.x, i = blockIdx.x * 256 + t;
  sh[t] = (i < N) ? deg[i] : 0;
  __syncthreads();
  for (int o = 128; o > 0; o >>= 1) {
    if (t < o) sh[t] += sh[t + o];
    __syncthreads();
  }
  if (t == 0) partial[blockIdx.x] = sh[0];
}

__global__ __launch_bounds__(512) void k_scanpartial(int* __restrict__ partial, int nb) {
  __shared__ int sh[512];
  int t = threadIdx.x;
  int v = (t < nb) ? partial[t] : 0;
  sh[t] = v;
  __syncthreads();
  for (int o = 1; o < 512; o <<= 1) {
    int x = (t >= o) ? sh[t - o] : 0;
    __syncthreads();
    sh[t] += x;
    __syncthreads();
  }
  if (t < nb) partial[t] = sh[t] - v;   // exclusive
}

__global__ __launch_bounds__(256) void k_scanblock(int* __restrict__ deg,
    const int* __restrict__ partial, int* __restrict__ off,
    float* __restrict__ dinv, int N) {
  __shared__ int sh[256];
  int t = threadIdx.x, b = blockIdx.x, i = b * 256 + t;
  int v = (i < N) ? deg[i] : 0;
  sh[t] = v;
  __syncthreads();
  for (int o = 1; o < 256; o <<= 1) {
    int x = (t >= o) ? sh[t - o] : 0;
    __syncthreads();
    sh[t] += x;
    __syncthreads();
  }
  if (i < N) {
    int excl = partial[b] + sh[t] - v;
    off[i] = excl;
    deg[i] = excl;                       // becomes fill cursor
    dinv[i] = rsqrtf((float)v + 1.0f);   // +1 self-loop
    if (i == N - 1) off[N] = excl + v;
  }
}

__global__ __launch_bounds__(256) void k_fillcsr(const int* __restrict__ rows,
    const int* __restrict__ cols, int* __restrict__ cursor,
    int* __restrict__ csrsrc, int E) {
  int e = blockIdx.x * 256 + threadIdx.x;
  if (e < E) {
    int pos = atomicAdd(&cursor[cols[e]], 1);
    csrsrc[pos] = rows[e];
  }
}

__global__ __launch_bounds__(256) void k_goff(const int* __restrict__ batch,
                                              int* __restrict__ goff, int N, int G) {
  int g = blockIdx.x * 256 + threadIdx.x;
  if (g > G) return;
  int lo = 0, hi = N;
  while (lo < hi) {
    int m = (lo + hi) >> 1;
    if (batch[m] < g) lo = m + 1; else hi = m;
  }
  goff[g] = lo;
}

// ---------- GEMM1 (split MFMA): y[v,:] = dinv[v] * (x[v,:] @ W1), fp32 out ----------
__global__ __launch_bounds__(256) void k_gemm1_mfma(
    const float* __restrict__ x,
    const unsigned short* __restrict__ W1th, const unsigned short* __restrict__ W1tl,
    const float* __restrict__ dinv, float* __restrict__ y, int N)
{
  const int tid = threadIdx.x;
  const int w = tid >> 6, l = tid & 63;
  const int v0 = blockIdx.x * 64;
  const int l15 = l & 15, lh = l >> 4;

  // preload B-frags: 2 col-tiles x 4 k-steps, hi+lo
  short8 bh[2][4], bl[2][4];
#pragma unroll
  for (int ct = 0; ct < 2; ++ct) {
    int colr = 32 * w + 16 * ct + l15;
#pragma unroll
    for (int ks = 0; ks < 4; ++ks) {
      bh[ct][ks] = *(const short8*)(W1th + colr * 128 + ks * 32 + 8 * lh);
      bl[ct][ks] = *(const short8*)(W1tl + colr * 128 + ks * 32 + 8 * lh);
    }
  }

#pragma unroll
  for (int rt = 0; rt < 4; ++rt) {
    int arow = v0 + rt * 16 + l15; if (arow >= N) arow = N - 1;
    const float* ar = x + (size_t)arow * 128 + 8 * lh;
    f32x4 acc0 = {0.f, 0.f, 0.f, 0.f}, acc1 = {0.f, 0.f, 0.f, 0.f};
#pragma unroll
    for (int ks = 0; ks < 4; ++ks) {
      float4 fa = *(const float4*)(ar + ks * 32);
      float4 fb = *(const float4*)(ar + ks * 32 + 4);
      short8 ah, al;
      float v0f;
      v0f = fa.x; ah[0] = (short)bf_rne(v0f); al[0] = (short)bf_rne(v0f - bf2f((unsigned short)ah[0]));
      v0f = fa.y; ah[1] = (short)bf_rne(v0f); al[1] = (short)bf_rne(v0f - bf2f((unsigned short)ah[1]));
      v0f = fa.z; ah[2] = (short)bf_rne(v0f); al[2] = (short)bf_rne(v0f - bf2f((unsigned short)ah[2]));
      v0f = fa.w; ah[3] = (short)bf_rne(v0f); al[3] = (short)bf_rne(v0f - bf2f((unsigned short)ah[3]));
      v0f = fb.x; ah[4] = (short)bf_rne(v0f); al[4] = (short)bf_rne(v0f - bf2f((unsigned short)ah[4]));
      v0f = fb.y; ah[5] = (short)bf_rne(v0f); al[5] = (short)bf_rne(v0f - bf2f((unsigned short)ah[5]));
      v0f = fb.z; ah[6] = (short)bf_rne(v0f); al[6] = (short)bf_rne(v0f - bf2f((unsigned short)ah[6]));
      v0f = fb.w; ah[7] = (short)bf_rne(v0f); al[7] = (short)bf_rne(v0f - bf2f((unsigned short)ah[7]));
      acc0 = __builtin_amdgcn_mfma_f32_16x16x32_bf16(ah, bh[0][ks], acc0, 0, 0, 0);
      acc0 = __builtin_amdgcn_mfma_f32_16x16x32_bf16(al, bh[0][ks], acc0, 0, 0, 0);
      acc0 = __builtin_amdgcn_mfma_f32_16x16x32_bf16(ah, bl[0][ks], acc0, 0, 0, 0);
      acc1 = __builtin_amdgcn_mfma_f32_16x16x32_bf16(ah, bh[1][ks], acc1, 0, 0, 0);
      acc1 = __builtin_amdgcn_mfma_f32_16x16x32_bf16(al, bh[1][ks], acc1, 0, 0, 0);
      acc1 = __builtin_amdgcn_mfma_f32_16x16x32_bf16(ah, bl[1][ks], acc1, 0, 0, 0);
    }

    int r4 = v0 + rt * 16 + lh * 4;
    float4 d4 = *(const float4*)(dinv + r4);   // may overread into deg region; stores guarded
    int col0 = 32 * w + l15;
#pragma unroll
    for (int reg = 0; reg < 4; ++reg) {
      int row = r4 + reg;
      if (row < N) {
        float dd = (reg == 0) ? d4.x : (reg == 1) ? d4.y : (reg == 2) ? d4.z : d4.w;
        y[(size_t)row * 128 + col0]      = acc0[reg] * dd;
        y[(size_t)row * 128 + col0 + 16] = acc1[reg] * dd;
      }
    }
  }
}

// ---------- GEMM2 fused with layer-1 aggregation (split MFMA) ----------
// Swizzle note: store byte = (vn*256 + dim*2) ^ ((vn&7)<<4); XOR mask covers
// bits 4-6, so the read address must be FULLY composed before the XOR:
//   read byte = (row*256 + ks*64 + lh*16) ^ ((row&7)<<4)
// (round-4/5 bug: adding ks*64 AFTER the XOR carried past bit 6 -> OOB LDS reads/NaN)
__global__ __launch_bounds__(256) void k_gemm2_fused_mfma(
    const float* __restrict__ y, const int* __restrict__ off,
    const int* __restrict__ src,
    const unsigned short* __restrict__ W2th, const unsigned short* __restrict__ W2tl,
    const float* __restrict__ dinv, const float* __restrict__ b1,
    float* __restrict__ z, int N)
{
  __shared__ unsigned short hh[64 * 128];   // 16 KB, XOR-swizzled
  __shared__ unsigned short hl[64 * 128];   // 16 KB, XOR-swizzled
  const int tid = threadIdx.x;
  const int w = tid >> 6, l = tid & 63;
  const int v0 = blockIdx.x * 64;
  const int l15 = l & 15, lh = l >> 4;

  // W2 B-frags hi/lo: 1 col-tile x 4 k-steps
  short8 bh[4], bl[4];
  {
    int colr = 16 * w + l15;
#pragma unroll
    for (int ks = 0; ks < 4; ++ks) {
      bh[ks] = *(const short8*)(W2th + colr * 128 + ks * 32 + 8 * lh);
      bl[ks] = *(const short8*)(W2tl + colr * 128 + ks * 32 + 8 * lh);
    }
  }

  { // gather phase: 4 threads/node, 32 dims each, fp32, MLP-2
    int vn = tid >> 2;
    int c0 = (tid & 3) * 32;
    int vv = v0 + vn;
    int vc = (vv < N) ? vv : N - 1;
    float acc[32];
    {
      const float4* yr = (const float4*)(y + (size_t)vc * 128 + c0);
#pragma unroll
      for (int q = 0; q < 8; ++q) {
        float4 t = yr[q];
        acc[4*q+0] = t.x; acc[4*q+1] = t.y; acc[4*q+2] = t.z; acc[4*q+3] = t.w;
      }
    }
    int e0 = off[vc], e1 = off[vc + 1];
    int last = e1 - 1;
    for (int i = e0; i < e1; i += 2) {
      int i1 = i + 1;
      int u0 = src[i];
      int u1 = src[i1 <= last ? i1 : last];
      float m1 = (i1 <= last) ? 1.f : 0.f;
      const float4* p0 = (const float4*)(y + (size_t)u0 * 128 + c0);
      const float4* p1 = (const float4*)(y + (size_t)u1 * 128 + c0);
#pragma unroll
      for (int q = 0; q < 8; ++q) {
        float4 t0 = p0[q], t1 = p1[q];
        acc[4*q+0] += t0.x + m1 * t1.x;
        acc[4*q+1] += t0.y + m1 * t1.y;
        acc[4*q+2] += t0.z + m1 * t1.z;
        acc[4*q+3] += t0.w + m1 * t1.w;
      }
    }
    float d = dinv[vc];
    // h = relu(d*acc + b1) -> split bf16 -> swizzled LDS (row = vn)
#pragma unroll
    for (int s = 0; s < 4; ++s) {
      short8 oh, ol;
#pragma unroll
      for (int j = 0; j < 8; ++j) {
        int dim = c0 + s * 8 + j;
        float hv = fmaxf(fmaf(d, acc[s*8+j], b1[dim]), 0.f);
        unsigned short hb = bf_rne(hv);
        oh[j] = (short)hb;
        ol[j] = (short)bf_rne(hv - bf2f(hb));
      }
      int byte = (vn * 256 + (c0 + s * 8) * 2) ^ ((vn & 7) << 4);
      *(short8*)((char*)hh + byte) = oh;
      *(short8*)((char*)hl + byte) = ol;
    }
  }
  __syncthreads();

  // MFMA phase: 12 MFMAs per row-tile
#pragma unroll
  for (int rt = 0; rt < 4; ++rt) {
    int row = rt * 16 + l15;
    const int swz = (row & 7) << 4;
    const int base = row * 256 + lh * 16;
    f32x4 acc = {0.f, 0.f, 0.f, 0.f};
#pragma unroll
    for (int ks = 0; ks < 4; ++ks) {
      int byte = (base + ks * 64) ^ swz;      // compose THEN xor (bijective in-row)
      short8 ah = *(const short8*)((char*)hh + byte);
      short8 al = *(const short8*)((char*)hl + byte);
      acc = __builtin_amdgcn_mfma_f32_16x16x32_bf16(ah, bh[ks], acc, 0, 0, 0);
      acc = __builtin_amdgcn_mfma_f32_16x16x32_bf16(al, bh[ks], acc, 0, 0, 0);
      acc = __builtin_amdgcn_mfma_f32_16x16x32_bf16(ah, bl[ks], acc, 0, 0, 0);
    }

    int r4 = v0 + rt * 16 + lh * 4;
    float4 d4 = *(const float4*)(dinv + r4);
    int col = 16 * w + l15;
#pragma unroll
    for (int reg = 0; reg < 4; ++reg) {
      int rr = r4 + reg;
      if (rr < N) {
        float dd = (reg == 0) ? d4.x : (reg == 1) ? d4.y : (reg == 2) ? d4.z : d4.w;
        z[(size_t)rr * 64 + col] = acc[reg] * dd;
      }
    }
  }
}

// ---------- layer-2 aggregation + pool ----------
__global__ __launch_bounds__(256) void k_aggpool(
    const float* __restrict__ z, const int* __restrict__ off,
    const int* __restrict__ src, const float* __restrict__ dinv,
    const int* __restrict__ goff, float* __restrict__ out, int N)
{
  int g = blockIdx.x >> 3, seg = blockIdx.x & 7;
  int w = threadIdx.x >> 6, lane = threadIdx.x & 63;
  int lo = goff[g], hi = goff[g + 1];
  float acc = 0.f;
  for (int v = lo + seg * 4 + w; v < hi; v += 32) {
    float sv = z[(size_t)v * 64 + lane];
    int e0 = off[v], e1 = off[v + 1];
    int last = e1 - 1;
    for (int i = e0; i < e1; i += 4) {
      int i1 = i + 1, i2 = i + 2, i3 = i + 3;
      int u0 = src[i];
      int u1 = src[i1 <= last ? i1 : last];
      int u2 = src[i2 <= last ? i2 : last];
      int u3 = src[i3 <= last ? i3 : last];
      float a0 = z[(size_t)u0 * 64 + lane];
      float a1 = z[(size_t)u1 * 64 + lane];
      float a2 = z[(size_t)u2 * 64 + lane];
      float a3 = z[(size_t)u3 * 64 + lane];
      sv += a0;
      sv += (i1 <= last) ? a1 : 0.f;
      sv += (i2 <= last) ? a2 : 0.f;
      sv += (i3 <= last) ? a3 : 0.f;
    }
    acc = fmaf(dinv[v], sv, acc);
  }
  atomAddF(out + (size_t)g * 64 + lane, acc);
}

__global__ __launch_bounds__(256) void k_final(float* __restrict__ out,
    const int* __restrict__ goff, const float* __restrict__ b2, int total) {
  int i = blockIdx.x * 256 + threadIdx.x;
  if (i >= total) return;
  int g = i >> 6, d = i & 63;
  int n = goff[g + 1] - goff[g];
  out[i] = (n > 0) ? out[i] / (float)n + b2[d] : 0.f;
}

extern "C" void kernel_launch(void* const* d_in, const int* in_sizes, int n_in,
                              void* d_out, int out_size, void* d_ws, size_t ws_size,
                              hipStream_t stream) {
  const float* x     = (const float*)d_in[0];
  const int*   eidx  = (const int*)d_in[1];
  const int*   batch = (const int*)d_in[2];
  const float* W1    = (const float*)d_in[3];
  const float* b1    = (const float*)d_in[4];
  const float* W2    = (const float*)d_in[5];
  const float* b2    = (const float*)d_in[6];
  float* out = (float*)d_out;

  const int N = in_sizes[2];          // 100000
  const int E = in_sizes[1] / 2;      // 640000
  const int G = out_size / 64;        // 256

  const int* rows = eidx;             // sources
  const int* cols = eidx + E;         // targets

  // workspace: [y N*128 f][z N*64 f][W1th 16384 u16][W1tl 16384 u16][W2th 8192 u16][W2tl 8192 u16]
  //            [dinv N f][deg N i][off N+1 i][partial 512 i][goff G+1 i][csrsrc E i]
  float* y   = (float*)d_ws;
  float* z   = y + (size_t)N * 128;
  unsigned short* W1th = (unsigned short*)(z + (size_t)N * 64);
  unsigned short* W1tl = W1th + 16384;
  unsigned short* W2th = W1tl + 16384;
  unsigned short* W2tl = W2th + 8192;
  float* dinv    = (float*)(W2tl + 8192);
  int*   deg     = (int*)(dinv + N);
  int*   off     = deg + N;
  int*   partial = off + N + 1;
  int*   goff    = partial + 512;
  int*   csrsrc  = goff + G + 1;

  const int B = 256;
  const int nb = (N + B - 1) / B;     // 391 <= 512

  hipMemsetAsync(deg, 0, (size_t)N * sizeof(int), stream);
  hipMemsetAsync(d_out, 0, (size_t)out_size * sizeof(float), stream);

  // weight prep (split-transposed bf16)
  k_prepw<<<(16384 + 8192 + B - 1) / B, B, 0, stream>>>(W1, W2, W1th, W1tl, W2th, W2tl);

  // CSR build + dinv + graph offsets
  k_count<<<(E + B - 1) / B, B, 0, stream>>>(cols, deg, E);
  k_blocksum<<<nb, B, 0, stream>>>(deg, partial, N);
  k_scanpartial<<<1, 512, 0, stream>>>(partial, nb);
  k_scanblock<<<nb, B, 0, stream>>>(deg, partial, off, dinv, N);
  k_fillcsr<<<(E + B - 1) / B, B, 0, stream>>>(rows, cols, deg, csrsrc, E);
  k_goff<<<(G + 1 + B - 1) / B, B, 0, stream>>>(batch, goff, N, G);

  // layer 1 transform (split MFMA)
  k_gemm1_mfma<<<(N + 63) / 64, B, 0, stream>>>(x, W1th, W1tl, dinv, y, N);
  // layer 1 aggregate + relu + layer 2 transform (split MFMA)
  k_gemm2_fused_mfma<<<(N + 63) / 64, B, 0, stream>>>(y, off, csrsrc, W2th, W2tl, dinv, b1, z, N);
  // layer 2 aggregate + pool + finalize
  k_aggpool<<<G * 8, B, 0, stream>>>(z, off, csrsrc, dinv, goff, out, N);
  k_final<<<(out_size + B - 1) / B, B, 0, stream>>>(out, goff, b2, out_size);
}